// Round 1
// baseline (424.476 us; speedup 1.0000x reference)
//
#include <hip/hip_runtime.h>
#include <cstddef>

#define NEGC (-10000000000.0f)

// ---------------- workspace layout (float offsets) ----------------
// GIp   @ 0        : 4*160*3072 = 1966080   (reused later as resp: 8*160*1024)
// GHp   @ 1966080  : 4*160*3072 = 1966080   (reused later as ctxp: 4*160*1024)
// qp    @ 3932160  : 4*160*1024 = 655360
// h_new @ 4587520  : 160*1024   = 163840
// hb1   @ 4751360  : 160
// attn  @ 4751520  : 160*512    = 81920
// align @ 4833440  : 160*512    = 81920
// logsc @ 4915360  : 800
// ctxe  @ 4916160  : 160*1024   = 163840
// cat   @ 5080000  : 160*2048   = 327680
// ints  @ 5407680  : sent 800, s_flat 160, new_sent 160
// total ~5.41M floats = 21.6 MB

// ---------------------------------------------------------------------------
// Generic skinny GEMM: C[z][160][N] = A[160, kslice of Ktot] @ W^T (NT) or @ W (NN)
// grid: (N/64, KSPLIT). Partial sums per z; consumers reduce.
// ---------------------------------------------------------------------------
template <bool NT>
__device__ __forceinline__ void gemm_body(const float* __restrict__ A,
                                          const float* __restrict__ W,
                                          float* __restrict__ Cp,
                                          int N, int Ktot, int n0, int z, int zcount) {
  __shared__ float As[160][36];
  __shared__ float Ws[64][36];
  const int KL = Ktot / zcount;
  const int kbase = z * KL;
  const int tid = threadIdx.x;
  const int tx = tid & 15, ty = tid >> 4;
  float acc[10][4];
#pragma unroll
  for (int i = 0; i < 10; ++i)
#pragma unroll
    for (int j = 0; j < 4; ++j) acc[i][j] = 0.f;

  for (int kt = 0; kt < KL; kt += 32) {
    const int kg = kbase + kt;
    for (int i = tid; i < 160 * 32; i += 256) {
      int m = i >> 5, kk = i & 31;
      As[m][kk] = A[(size_t)m * Ktot + kg + kk];
    }
    if (NT) {
      for (int i = tid; i < 64 * 32; i += 256) {
        int n = i >> 5, kk = i & 31;
        Ws[n][kk] = W[(size_t)(n0 + n) * Ktot + kg + kk];
      }
    } else {
      for (int i = tid; i < 64 * 32; i += 256) {
        int kk = i >> 6, n = i & 63;
        Ws[n][kk] = W[(size_t)(kg + kk) * N + n0 + n];
      }
    }
    __syncthreads();
    for (int kk = 0; kk < 32; kk += 4) {
      float4 a[10], w[4];
#pragma unroll
      for (int i = 0; i < 10; ++i)
        a[i] = *reinterpret_cast<const float4*>(&As[ty + 16 * i][kk]);
#pragma unroll
      for (int j = 0; j < 4; ++j)
        w[j] = *reinterpret_cast<const float4*>(&Ws[tx + 16 * j][kk]);
#pragma unroll
      for (int i = 0; i < 10; ++i)
#pragma unroll
        for (int j = 0; j < 4; ++j) {
          acc[i][j] += a[i].x * w[j].x;
          acc[i][j] += a[i].y * w[j].y;
          acc[i][j] += a[i].z * w[j].z;
          acc[i][j] += a[i].w * w[j].w;
        }
    }
    __syncthreads();
  }
  float* Co = Cp + (size_t)z * 160 * N + n0;
#pragma unroll
  for (int i = 0; i < 10; ++i)
#pragma unroll
    for (int j = 0; j < 4; ++j)
      Co[(size_t)(ty + 16 * i) * N + tx + 16 * j] = acc[i][j];
}

template <bool NT>
__global__ __launch_bounds__(256) void gemm_f32(const float* __restrict__ A,
                                                const float* __restrict__ W,
                                                float* __restrict__ Cp, int N, int Ktot) {
  gemm_body<NT>(A, W, Cp, N, Ktot, blockIdx.x * 64, blockIdx.y, gridDim.y);
}

// GI and GH in one launch (z axis picks which), N=3072, K=1024
__global__ __launch_bounds__(256) void gemm_gru(const float* __restrict__ X,
                                                const float* __restrict__ Hp,
                                                const float* __restrict__ Wih,
                                                const float* __restrict__ Whh,
                                                float* __restrict__ GIp,
                                                float* __restrict__ GHp) {
  const float* A = blockIdx.z ? Hp : X;
  const float* W = blockIdx.z ? Whh : Wih;
  float* Cp = blockIdx.z ? GHp : GIp;
  gemm_body<true>(A, W, Cp, 3072, 1024, blockIdx.x * 64, blockIdx.y, gridDim.y);
}

// ---------------------------------------------------------------------------
// GRU elementwise: sum K-split partials, gates, h_new; also fills cat[:,1024:]
// ---------------------------------------------------------------------------
__global__ void gru_k(const float* __restrict__ GIp, const float* __restrict__ GHp,
                      const float* __restrict__ bih, const float* __restrict__ bhh,
                      const float* __restrict__ hprev, float* __restrict__ h_new,
                      float* __restrict__ cat) {
  int idx = blockIdx.x * 256 + threadIdx.x;  // 160*1024
  int b = idx >> 10, h = idx & 1023;
  float gir = bih[h], giz = bih[1024 + h], gin = bih[2048 + h];
  float ghr = bhh[h], ghz = bhh[1024 + h], ghn = bhh[2048 + h];
#pragma unroll
  for (int z = 0; z < 4; ++z) {
    size_t base = ((size_t)z * 160 + b) * 3072;
    gir += GIp[base + h]; giz += GIp[base + 1024 + h]; gin += GIp[base + 2048 + h];
    ghr += GHp[base + h]; ghz += GHp[base + 1024 + h]; ghn += GHp[base + 2048 + h];
  }
  float r = 1.0f / (1.0f + expf(-(gir + ghr)));
  float zg = 1.0f / (1.0f + expf(-(giz + ghz)));
  float n = tanhf(gin + r * ghn);
  float hp = hprev[idx];
  float hn = (1.0f - zg) * n + zg * hp;
  h_new[idx] = hn;
  cat[(size_t)b * 2048 + 1024 + h] = hn;
}

// hb1[b] = dot(h_new[b], b1)
__global__ void hb1_k(const float* __restrict__ h_new, const float* __restrict__ b1,
                      float* __restrict__ hb1) {
  int b = blockIdx.x, t = threadIdx.x;
  float s = 0.f;
  for (int k = t; k < 1024; k += 256) s += h_new[(size_t)b * 1024 + k] * b1[k];
  __shared__ float red[256];
  red[t] = s; __syncthreads();
  for (int o = 128; o > 0; o >>= 1) { if (t < o) red[t] += red[t + o]; __syncthreads(); }
  if (t == 0) hb1[b] = red[0];
}

// ---------------------------------------------------------------------------
// Pass 1 over encoder_outputs: attn[b,s] = (enc[b,s]·q[b] + h·b1)/32 + mask
// grid (160, 4) x 256 threads; each block: 128 s-rows, one per wave per iter
// ---------------------------------------------------------------------------
__global__ __launch_bounds__(256) void scores_k(const float* __restrict__ enc,
                                                const float* __restrict__ qp,
                                                const float* __restrict__ hb1,
                                                const float* __restrict__ maskin,
                                                float* __restrict__ attn) {
  int b = blockIdx.x, sc = blockIdx.y;
  int tid = threadIdx.x;
  __shared__ float4 qs[256];
  float4 a = {0.f, 0.f, 0.f, 0.f};
#pragma unroll
  for (int z = 0; z < 4; ++z) {
    const float4 t = *reinterpret_cast<const float4*>(&qp[((size_t)z * 160 + b) * 1024 + 4 * tid]);
    a.x += t.x; a.y += t.y; a.z += t.z; a.w += t.w;
  }
  qs[tid] = a;
  __syncthreads();
  int wave = tid >> 6, lane = tid & 63;
  float hb = hb1[b] * 0.03125f;
  for (int i = 0; i < 32; ++i) {
    int s = sc * 128 + wave + 4 * i;
    const float4* row = reinterpret_cast<const float4*>(enc + ((size_t)b * 512 + s) * 1024);
    float sum = 0.f;
#pragma unroll
    for (int j = 0; j < 4; ++j) {
      float4 e = row[lane + 64 * j];
      float4 q = qs[lane + 64 * j];
      sum += e.x * q.x + e.y * q.y + e.z * q.z + e.w * q.w;
    }
#pragma unroll
    for (int off = 32; off > 0; off >>= 1) sum += __shfl_xor(sum, off);
    if (lane == 0)
      attn[(size_t)b * 512 + s] = sum * 0.03125f + hb + maskin[(size_t)b * 512 + s];
  }
}

// ---------------------------------------------------------------------------
// softmax + top-5 per batch row (tie: lower index, matching lax.top_k)
// ---------------------------------------------------------------------------
__global__ __launch_bounds__(256) void smtopk_k(const float* __restrict__ attn,
                                                const float* __restrict__ ev,
                                                float* __restrict__ align,
                                                float* __restrict__ logsc,
                                                int* __restrict__ sent) {
  int b = blockIdx.x, t = threadIdx.x;
  __shared__ float v[512];
  __shared__ float red[256];
  __shared__ int redi[256];
  float x0 = attn[(size_t)b * 512 + t], x1 = attn[(size_t)b * 512 + 256 + t];
  red[t] = fmaxf(x0, x1); __syncthreads();
  for (int o = 128; o > 0; o >>= 1) { if (t < o) red[t] = fmaxf(red[t], red[t + o]); __syncthreads(); }
  float mx = red[0]; __syncthreads();
  float p0 = expf(x0 - mx), p1 = expf(x1 - mx);
  red[t] = p0 + p1; __syncthreads();
  for (int o = 128; o > 0; o >>= 1) { if (t < o) red[t] += red[t + o]; __syncthreads(); }
  float Z = red[0]; __syncthreads();
  float a0 = p0 / Z, a1 = p1 / Z;
  align[(size_t)b * 512 + t] = a0;
  align[(size_t)b * 512 + 256 + t] = a1;
  v[t] = a0; v[t + 256] = a1;
  __syncthreads();
  for (int r = 0; r < 5; ++r) {
    float bv; int bi;
    float v0 = v[t], v1 = v[t + 256];
    if (v1 > v0) { bv = v1; bi = t + 256; } else { bv = v0; bi = t; }
    red[t] = bv; redi[t] = bi; __syncthreads();
    for (int o = 128; o > 0; o >>= 1) {
      if (t < o) {
        if (red[t + o] > red[t] || (red[t + o] == red[t] && redi[t + o] < redi[t])) {
          red[t] = red[t + o]; redi[t] = redi[t + o];
        }
      }
      __syncthreads();
    }
    if (t == 0) {
      int id = redi[0]; float sc = red[0];
      sent[b * 5 + r] = id;
      logsc[b * 5 + r] = -logf(sc) + ev[b];
      v[id] = -1.0f;
    }
    __syncthreads();
  }
}

// ---------------------------------------------------------------------------
// beam re-ranking: per base group, 5 smallest of 25 (stable ascending)
// writes s_flat/new_sent (ws) + ev_idx_new + new_evidence_scores (d_out)
// ---------------------------------------------------------------------------
__global__ void beam_k(const float* __restrict__ logsc, const int* __restrict__ sent,
                       const int* __restrict__ evidx_in, int* __restrict__ s_flat,
                       int* __restrict__ new_sent, float* __restrict__ out) {
  int g = blockIdx.x;
  int lane = threadIdx.x;  // 64
  float val = 1e30f;
  if (lane < 25) val = logsc[(g * 5 + lane / 5) * 5 + (lane % 5)];
  for (int j = 0; j < 5; ++j) {
    float bv = val; int bi = lane;
#pragma unroll
    for (int off = 1; off < 64; off <<= 1) {
      float ov = __shfl_xor(bv, off);
      int oi = __shfl_xor(bi, off);
      if (ov < bv || (ov == bv && oi < bi)) { bv = ov; bi = oi; }
    }
    if (lane == 0) {
      int ii = bi / 5, rr = bi % 5;
      int bp = g * 5 + j, sf = g * 5 + ii;
      s_flat[bp] = sf;
      int ns = sent[sf * 5 + rr];
      new_sent[bp] = ns;
      out[820000 + bp] = bv;
      for (int tt = 0; tt < 4; ++tt)
        out[327680 + bp * 5 + tt] = (float)evidx_in[sf * 4 + tt];
      out[327680 + bp * 5 + 4] = (float)ns;
    }
    if (lane == bi) val = 1e30f;
  }
}

// ---------------------------------------------------------------------------
// Pass 2 over encoder_outputs: ctxe[b,k] = sum_s align[b,s]*enc[b,s,k]
// grid (160, 4) x 64 threads (float4 per lane => 256 k per block)
// ---------------------------------------------------------------------------
__global__ __launch_bounds__(64) void ctxe_k(const float* __restrict__ enc,
                                             const float* __restrict__ align,
                                             float* __restrict__ ctxe) {
  int b = blockIdx.x, q = blockIdx.y, lane = threadIdx.x;
  __shared__ float al[512];
  for (int i = lane; i < 512; i += 64) al[i] = align[(size_t)b * 512 + i];
  __syncthreads();
  const float4* base = reinterpret_cast<const float4*>(enc) + (size_t)b * 512 * 256 + q * 64 + lane;
  float4 acc0 = {0.f, 0.f, 0.f, 0.f}, acc1 = {0.f, 0.f, 0.f, 0.f};
#pragma unroll 4
  for (int s = 0; s < 512; s += 2) {
    float a0 = al[s], a1 = al[s + 1];
    float4 e0 = base[(size_t)s * 256];
    float4 e1 = base[(size_t)(s + 1) * 256];
    acc0.x += a0 * e0.x; acc0.y += a0 * e0.y; acc0.z += a0 * e0.z; acc0.w += a0 * e0.w;
    acc1.x += a1 * e1.x; acc1.y += a1 * e1.y; acc1.z += a1 * e1.z; acc1.w += a1 * e1.w;
  }
  float4 r;
  r.x = acc0.x + acc1.x; r.y = acc0.y + acc1.y; r.z = acc0.z + acc1.z; r.w = acc0.w + acc1.w;
  reinterpret_cast<float4*>(ctxe)[(size_t)b * 256 + q * 64 + lane] = r;
}

// cat[b, 0:1024] = sum_z ctxp + b2
__global__ void sumcat_k(const float* __restrict__ ctxp, const float* __restrict__ b2,
                         float* __restrict__ cat) {
  int idx = blockIdx.x * 256 + threadIdx.x;  // 160*1024
  int b = idx >> 10, j = idx & 1023;
  float v = b2[j];
#pragma unroll
  for (int z = 0; z < 4; ++z) v += ctxp[((size_t)z * 160 + b) * 1024 + j];
  cat[(size_t)b * 2048 + j] = v;
}

// ---------------------------------------------------------------------------
// final gather/pack of result_new, hidden_new, attn_scores_new, mask_new
// ---------------------------------------------------------------------------
__global__ void pack_k(const float* __restrict__ resp, const float* __restrict__ b3,
                       const float* __restrict__ h_new, const float* __restrict__ attn_sc_in,
                       const float* __restrict__ attn, const float* __restrict__ mask_in,
                       const int* __restrict__ s_flat, const int* __restrict__ new_sent,
                       float* __restrict__ out) {
  int idx = blockIdx.x * 256 + threadIdx.x;  // 819200
  if (idx < 163840) {  // result_new
    int bp = idx >> 10, k = idx & 1023;
    int sf = s_flat[bp];
    float v = b3[k];
#pragma unroll
    for (int z = 0; z < 8; ++z) v += resp[((size_t)z * 160 + sf) * 1024 + k];
    out[idx] = v;
  } else if (idx < 327680) {  // hidden_new
    int rel = idx - 163840;
    int bp = rel >> 10, k = rel & 1023;
    out[idx] = h_new[(size_t)s_flat[bp] * 1024 + k];
  } else if (idx < 737280) {  // attn_scores_new (5,160,1,512), +800 for ev_idx region
    int rel = idx - 327680;
    int t = rel / 81920, r2 = rel % 81920;
    int bp = r2 >> 9, s = r2 & 511;
    int sf = s_flat[bp];
    float v = (t < 4) ? attn_sc_in[((size_t)t * 160 + sf) * 512 + s]
                      : attn[(size_t)sf * 512 + s];
    out[328480 + rel] = v;
  } else {  // mask_new
    int rel = idx - 737280;
    int bp = rel >> 9, s = rel & 511;
    int sf = s_flat[bp];
    float v = (s == new_sent[bp]) ? NEGC : mask_in[(size_t)sf * 512 + s];
    out[738080 + rel] = v;
  }
}

extern "C" void kernel_launch(void* const* d_in, const int* in_sizes, int n_in,
                              void* d_out, int out_size, void* d_ws, size_t ws_size,
                              hipStream_t stream) {
  const float* last_hidden = (const float*)d_in[0];
  const float* dec_in      = (const float*)d_in[1];
  const float* enc         = (const float*)d_in[2];
  const float* attn_sc_in  = (const float*)d_in[3];
  const float* mask_in     = (const float*)d_in[4];
  const float* ev          = (const float*)d_in[5];
  const int*   evidx       = (const int*)d_in[6];
  const float* W1  = (const float*)d_in[7];
  const float* b1  = (const float*)d_in[8];
  const float* W2  = (const float*)d_in[9];
  const float* b2  = (const float*)d_in[10];
  const float* W3  = (const float*)d_in[11];
  const float* b3  = (const float*)d_in[12];
  const float* Wih = (const float*)d_in[13];
  const float* Whh = (const float*)d_in[14];
  const float* bih = (const float*)d_in[15];
  const float* bhh = (const float*)d_in[16];
  float* out = (float*)d_out;
  float* ws = (float*)d_ws;

  float* GIp   = ws;
  float* GHp   = ws + 1966080;
  float* qp    = ws + 3932160;
  float* h_new = ws + 4587520;
  float* hb1   = ws + 4751360;
  float* attn  = ws + 4751520;
  float* align = ws + 4833440;
  float* logsc = ws + 4915360;
  float* ctxe  = ws + 4916160;
  float* cat   = ws + 5080000;
  int* sent     = (int*)(ws + 5407680);
  int* s_flat   = sent + 800;
  int* new_sent = s_flat + 160;
  float* resp = GIp;  // GIp consumed by gru_k before result GEMM writes
  float* ctxp = GHp;  // GHp consumed by gru_k before context GEMM writes

  gemm_gru<<<dim3(48, 4, 2), dim3(256), 0, stream>>>(dec_in, last_hidden, Wih, Whh, GIp, GHp);
  gru_k<<<dim3(640), dim3(256), 0, stream>>>(GIp, GHp, bih, bhh, last_hidden, h_new, cat);
  hb1_k<<<dim3(160), dim3(256), 0, stream>>>(h_new, b1, hb1);
  gemm_f32<false><<<dim3(16, 4), dim3(256), 0, stream>>>(h_new, W1, qp, 1024, 1024);
  scores_k<<<dim3(160, 4), dim3(256), 0, stream>>>(enc, qp, hb1, mask_in, attn);
  smtopk_k<<<dim3(160), dim3(256), 0, stream>>>(attn, ev, align, logsc, sent);
  beam_k<<<dim3(32), dim3(64), 0, stream>>>(logsc, sent, evidx, s_flat, new_sent, out);
  ctxe_k<<<dim3(160, 4), dim3(64), 0, stream>>>(enc, align, ctxe);
  gemm_f32<true><<<dim3(16, 4), dim3(256), 0, stream>>>(ctxe, W2, ctxp, 1024, 1024);
  sumcat_k<<<dim3(640), dim3(256), 0, stream>>>(ctxp, b2, cat);
  gemm_f32<true><<<dim3(16, 8), dim3(256), 0, stream>>>(cat, W3, resp, 1024, 2048);
  pack_k<<<dim3(3200), dim3(256), 0, stream>>>(resp, b3, h_new, attn_sc_in, attn, mask_in,
                                               s_flat, new_sent, out);
}

// Round 2
// 368.949 us; speedup vs baseline: 1.1505x; 1.1505x over previous
//
#include <hip/hip_runtime.h>
#include <cstddef>

#define NEGC (-10000000000.0f)

// ---------------- workspace layout (float offsets) ----------------
// resp/GIp @ 0        : 12*160*1024 = 1966080 (GRU GI partials first, then result partials)
// ctxp/GHp @ 1966080  : 4*160*3072 = 1966080 (GRU GH partials, then W2 out partials 8*163840)
// qp/ctxep/context @ 3932160 : 4*160*1024 = 655360
// h_new    @ 4587520  : 163840
// hb1      @ 4751360  : 160
// attn     @ 4751520  : 81920
// align    @ 4833440  : 81920
// logsc    @ 4915360  : 800
// ints     @ 4916160  : sent 800, s_flat 160, new_sent 160

// ---------------------------------------------------------------------------
// Skinny GEMM: C[z][160][64-strip] = A[160, k-slice] @ W (NN) or @ W^T (NT)
// A row stride fixed 1024. AMODE 1: A = bias[k] + sum of pcount partials
// spaced 163840 floats. Output is a K-split partial per z.
// ---------------------------------------------------------------------------
template <bool NT, int AMODE>
__device__ __forceinline__ void gemm_body2(const float* __restrict__ A, int pcount,
                                           const float* __restrict__ bias,
                                           const float* __restrict__ W, int ldw, int woff,
                                           float* __restrict__ Co, int N, int Ktot,
                                           int n0, int z, int zcount) {
  __shared__ float As[160][36];
  __shared__ float Ws[64][36];
  const int KL = Ktot / zcount;
  const int kbase = z * KL;
  const int tid = threadIdx.x;
  const int tx = tid & 15, ty = tid >> 4;
  float acc[10][4];
#pragma unroll
  for (int i = 0; i < 10; ++i)
#pragma unroll
    for (int j = 0; j < 4; ++j) acc[i][j] = 0.f;

  for (int kt = 0; kt < KL; kt += 32) {
    const int kg = kbase + kt;
    for (int i = tid; i < 160 * 32; i += 256) {
      int m = i >> 5, kk = i & 31;
      float v;
      if (AMODE == 0) {
        v = A[(size_t)m * 1024 + kg + kk];
      } else {
        v = bias ? bias[kg + kk] : 0.f;
        for (int p = 0; p < pcount; ++p)
          v += A[(size_t)p * 163840 + (size_t)m * 1024 + kg + kk];
      }
      As[m][kk] = v;
    }
    if (NT) {
      for (int i = tid; i < 64 * 32; i += 256) {
        int n = i >> 5, kk = i & 31;
        Ws[n][kk] = W[(size_t)(n0 + n) * ldw + woff + kg + kk];
      }
    } else {
      for (int i = tid; i < 64 * 32; i += 256) {
        int kk = i >> 6, n = i & 63;
        Ws[n][kk] = W[(size_t)(kg + kk) * ldw + n0 + n];
      }
    }
    __syncthreads();
    for (int kk = 0; kk < 32; kk += 4) {
      float4 a[10], w[4];
#pragma unroll
      for (int i = 0; i < 10; ++i)
        a[i] = *reinterpret_cast<const float4*>(&As[ty + 16 * i][kk]);
#pragma unroll
      for (int j = 0; j < 4; ++j)
        w[j] = *reinterpret_cast<const float4*>(&Ws[tx + 16 * j][kk]);
#pragma unroll
      for (int i = 0; i < 10; ++i)
#pragma unroll
        for (int j = 0; j < 4; ++j) {
          acc[i][j] += a[i].x * w[j].x;
          acc[i][j] += a[i].y * w[j].y;
          acc[i][j] += a[i].z * w[j].z;
          acc[i][j] += a[i].w * w[j].w;
        }
    }
    __syncthreads();
  }
  float* Cb = Co + (size_t)z * 160 * N + n0;
#pragma unroll
  for (int i = 0; i < 10; ++i)
#pragma unroll
    for (int j = 0; j < 4; ++j)
      Cb[(size_t)(ty + 16 * i) * N + tx + 16 * j] = acc[i][j];
}

// GRU input/hidden GEMMs, one launch (blockIdx.z selects matrix), N=3072
__global__ __launch_bounds__(256) void k_gemm_gru(const float* __restrict__ X,
                                                  const float* __restrict__ H0,
                                                  const float* __restrict__ Wih,
                                                  const float* __restrict__ Whh,
                                                  float* __restrict__ GIp,
                                                  float* __restrict__ GHp) {
  const float* A = blockIdx.z ? H0 : X;
  const float* W = blockIdx.z ? Whh : Wih;
  float* C = blockIdx.z ? GHp : GIp;
  gemm_body2<true, 0>(A, 0, nullptr, W, 1024, 0, C, 3072, 1024,
                      blockIdx.x * 64, blockIdx.y, gridDim.y);
}

// q = h @ W1 (NN) and resB = h @ W3[:,1024:]^T (NT) in one launch
__global__ __launch_bounds__(256) void k_gemm_qw3b(const float* __restrict__ h,
                                                   const float* __restrict__ W1,
                                                   const float* __restrict__ W3,
                                                   float* __restrict__ qp,
                                                   float* __restrict__ respB) {
  if (blockIdx.z == 0)
    gemm_body2<false, 0>(h, 0, nullptr, W1, 1024, 0, qp, 1024, 1024,
                         blockIdx.x * 64, blockIdx.y, gridDim.y);
  else
    gemm_body2<true, 0>(h, 0, nullptr, W3, 2048, 1024, respB, 1024, 1024,
                        blockIdx.x * 64, blockIdx.y, gridDim.y);
}

// ctx-partials = (sum of 4 ctxep chunks) @ W2^T
__global__ __launch_bounds__(256) void k_gemm_w2(const float* __restrict__ ctxep,
                                                 const float* __restrict__ W2,
                                                 float* __restrict__ ctxp) {
  gemm_body2<true, 1>(ctxep, 4, nullptr, W2, 1024, 0, ctxp, 1024, 1024,
                      blockIdx.x * 64, blockIdx.y, gridDim.y);
}

// resp[0..7] = context @ W3[:, :1024]^T
__global__ __launch_bounds__(256) void k_gemm_w3a(const float* __restrict__ context,
                                                  const float* __restrict__ W3,
                                                  float* __restrict__ resp) {
  gemm_body2<true, 0>(context, 0, nullptr, W3, 2048, 0, resp, 1024, 1024,
                      blockIdx.x * 64, blockIdx.y, gridDim.y);
}

// context[b][j] = b2[j] + sum_z ctxp[z][b][j]
__global__ void sumctx_k(const float* __restrict__ ctxp, const float* __restrict__ b2,
                         float* __restrict__ context) {
  int idx = blockIdx.x * 256 + threadIdx.x;  // 163840
  int j = idx & 1023;
  float v = b2[j];
#pragma unroll
  for (int z = 0; z < 8; ++z) v += ctxp[(size_t)z * 163840 + idx];
  context[idx] = v;
}

// ---------------------------------------------------------------------------
// GRU elementwise + fused hb1 = dot(h_new[b], b1). grid 160, block 256.
// ---------------------------------------------------------------------------
__global__ __launch_bounds__(256) void gru_k(const float* __restrict__ GIp,
                                             const float* __restrict__ GHp,
                                             const float* __restrict__ bih,
                                             const float* __restrict__ bhh,
                                             const float* __restrict__ hprev,
                                             const float* __restrict__ b1,
                                             float* __restrict__ h_new,
                                             float* __restrict__ hb1) {
  int b = blockIdx.x, t = threadIdx.x;
  float dot = 0.f;
#pragma unroll
  for (int u = 0; u < 4; ++u) {
    int h = t + 256 * u;
    float gir = bih[h], giz = bih[1024 + h], gin = bih[2048 + h];
    float ghr = bhh[h], ghz = bhh[1024 + h], ghn = bhh[2048 + h];
#pragma unroll
    for (int z = 0; z < 4; ++z) {
      size_t base = ((size_t)z * 160 + b) * 3072 + h;
      gir += GIp[base]; giz += GIp[base + 1024]; gin += GIp[base + 2048];
      ghr += GHp[base]; ghz += GHp[base + 1024]; ghn += GHp[base + 2048];
    }
    float r = 1.0f / (1.0f + expf(-(gir + ghr)));
    float zg = 1.0f / (1.0f + expf(-(giz + ghz)));
    float n = tanhf(gin + r * ghn);
    float hp = hprev[(size_t)b * 1024 + h];
    float hn = (1.0f - zg) * n + zg * hp;
    h_new[(size_t)b * 1024 + h] = hn;
    dot += hn * b1[h];
  }
  __shared__ float red[256];
  red[t] = dot; __syncthreads();
  for (int o = 128; o > 0; o >>= 1) { if (t < o) red[t] += red[t + o]; __syncthreads(); }
  if (t == 0) hb1[b] = red[0];
}

// ---------------------------------------------------------------------------
// Pass 1 over enc: attn[b,s] = (enc[b,s]·q[b] + h·b1)/32 + mask
// ---------------------------------------------------------------------------
__global__ __launch_bounds__(256) void scores_k(const float* __restrict__ enc,
                                                const float* __restrict__ qp,
                                                const float* __restrict__ hb1,
                                                const float* __restrict__ maskin,
                                                float* __restrict__ attn) {
  int b = blockIdx.x, sc = blockIdx.y;
  int tid = threadIdx.x;
  __shared__ float4 qs[256];
  float4 a = {0.f, 0.f, 0.f, 0.f};
#pragma unroll
  for (int z = 0; z < 4; ++z) {
    const float4 t = *reinterpret_cast<const float4*>(&qp[((size_t)z * 160 + b) * 1024 + 4 * tid]);
    a.x += t.x; a.y += t.y; a.z += t.z; a.w += t.w;
  }
  qs[tid] = a;
  __syncthreads();
  int wave = tid >> 6, lane = tid & 63;
  float hb = hb1[b] * 0.03125f;
  for (int i = 0; i < 32; ++i) {
    int s = sc * 128 + wave + 4 * i;
    const float4* row = reinterpret_cast<const float4*>(enc + ((size_t)b * 512 + s) * 1024);
    float sum = 0.f;
#pragma unroll
    for (int j = 0; j < 4; ++j) {
      float4 e = row[lane + 64 * j];
      float4 q = qs[lane + 64 * j];
      sum += e.x * q.x + e.y * q.y + e.z * q.z + e.w * q.w;
    }
#pragma unroll
    for (int off = 32; off > 0; off >>= 1) sum += __shfl_xor(sum, off);
    if (lane == 0)
      attn[(size_t)b * 512 + s] = sum * 0.03125f + hb + maskin[(size_t)b * 512 + s];
  }
}

// ---------------------------------------------------------------------------
// softmax + top-5 per batch row (tie: lower index, matching lax.top_k)
// ---------------------------------------------------------------------------
__global__ __launch_bounds__(256) void smtopk_k(const float* __restrict__ attn,
                                                const float* __restrict__ ev,
                                                float* __restrict__ align,
                                                float* __restrict__ logsc,
                                                int* __restrict__ sent) {
  int b = blockIdx.x, t = threadIdx.x;
  __shared__ float v[512];
  __shared__ float red[256];
  __shared__ int redi[256];
  float x0 = attn[(size_t)b * 512 + t], x1 = attn[(size_t)b * 512 + 256 + t];
  red[t] = fmaxf(x0, x1); __syncthreads();
  for (int o = 128; o > 0; o >>= 1) { if (t < o) red[t] = fmaxf(red[t], red[t + o]); __syncthreads(); }
  float mx = red[0]; __syncthreads();
  float p0 = expf(x0 - mx), p1 = expf(x1 - mx);
  red[t] = p0 + p1; __syncthreads();
  for (int o = 128; o > 0; o >>= 1) { if (t < o) red[t] += red[t + o]; __syncthreads(); }
  float Z = red[0]; __syncthreads();
  float a0 = p0 / Z, a1 = p1 / Z;
  align[(size_t)b * 512 + t] = a0;
  align[(size_t)b * 512 + 256 + t] = a1;
  v[t] = a0; v[t + 256] = a1;
  __syncthreads();
  for (int r = 0; r < 5; ++r) {
    float bv; int bi;
    float v0 = v[t], v1 = v[t + 256];
    if (v1 > v0) { bv = v1; bi = t + 256; } else { bv = v0; bi = t; }
    red[t] = bv; redi[t] = bi; __syncthreads();
    for (int o = 128; o > 0; o >>= 1) {
      if (t < o) {
        if (red[t + o] > red[t] || (red[t + o] == red[t] && redi[t + o] < redi[t])) {
          red[t] = red[t + o]; redi[t] = redi[t + o];
        }
      }
      __syncthreads();
    }
    if (t == 0) {
      int id = redi[0]; float sc = red[0];
      sent[b * 5 + r] = id;
      logsc[b * 5 + r] = -logf(sc) + ev[b];
      v[id] = -1.0f;
    }
    __syncthreads();
  }
}

// ---------------------------------------------------------------------------
// beam re-ranking: per base group, 5 smallest of 25 (stable ascending)
// ---------------------------------------------------------------------------
__global__ void beam_k(const float* __restrict__ logsc, const int* __restrict__ sent,
                       const int* __restrict__ evidx_in, int* __restrict__ s_flat,
                       int* __restrict__ new_sent, float* __restrict__ out) {
  int g = blockIdx.x;
  int lane = threadIdx.x;  // 64
  float val = 1e30f;
  if (lane < 25) val = logsc[(g * 5 + lane / 5) * 5 + (lane % 5)];
  for (int j = 0; j < 5; ++j) {
    float bv = val; int bi = lane;
#pragma unroll
    for (int off = 1; off < 64; off <<= 1) {
      float ov = __shfl_xor(bv, off);
      int oi = __shfl_xor(bi, off);
      if (ov < bv || (ov == bv && oi < bi)) { bv = ov; bi = oi; }
    }
    if (lane == 0) {
      int ii = bi / 5, rr = bi % 5;
      int bp = g * 5 + j, sf = g * 5 + ii;
      s_flat[bp] = sf;
      int ns = sent[sf * 5 + rr];
      new_sent[bp] = ns;
      out[820000 + bp] = bv;
      for (int tt = 0; tt < 4; ++tt)
        out[327680 + bp * 5 + tt] = (float)evidx_in[sf * 4 + tt];
      out[327680 + bp * 5 + 4] = (float)ns;
    }
    if (lane == bi) val = 1e30f;
  }
}

// ---------------------------------------------------------------------------
// Pass 2 over enc: ctxep[c][b][k] = sum_{s in chunk c} align[b,s]*enc[b,s,k]
// 256 threads, one float4 column slice per thread, 8 loads in flight.
// ---------------------------------------------------------------------------
__global__ __launch_bounds__(256) void ctxe_k(const float* __restrict__ enc,
                                              const float* __restrict__ align,
                                              float* __restrict__ ctxep) {
  int b = blockIdx.x, c = blockIdx.y, t = threadIdx.x;
  __shared__ float al[128];
  if (t < 128) al[t] = align[(size_t)b * 512 + c * 128 + t];
  __syncthreads();
  const float4* base = reinterpret_cast<const float4*>(enc) + ((size_t)b * 512 + c * 128) * 256 + t;
  float4 a0 = {0.f, 0.f, 0.f, 0.f}, a1 = {0.f, 0.f, 0.f, 0.f};
#pragma unroll 4
  for (int s = 0; s < 128; s += 2) {
    float w0 = al[s], w1 = al[s + 1];
    float4 e0 = base[(size_t)s * 256];
    float4 e1 = base[(size_t)(s + 1) * 256];
    a0.x += w0 * e0.x; a0.y += w0 * e0.y; a0.z += w0 * e0.z; a0.w += w0 * e0.w;
    a1.x += w1 * e1.x; a1.y += w1 * e1.y; a1.z += w1 * e1.z; a1.w += w1 * e1.w;
  }
  float4 r;
  r.x = a0.x + a1.x; r.y = a0.y + a1.y; r.z = a0.z + a1.z; r.w = a0.w + a1.w;
  reinterpret_cast<float4*>(ctxep)[((size_t)c * 160 + b) * 256 + t] = r;
}

// ---------------------------------------------------------------------------
// final gather/pack; resp has 12 partial slices (W3a z0..7, W3b z8..11)
// ---------------------------------------------------------------------------
__global__ void pack_k(const float* __restrict__ resp, const float* __restrict__ b3,
                       const float* __restrict__ h_new, const float* __restrict__ attn_sc_in,
                       const float* __restrict__ attn, const float* __restrict__ mask_in,
                       const int* __restrict__ s_flat, const int* __restrict__ new_sent,
                       float* __restrict__ out) {
  int idx = blockIdx.x * 256 + threadIdx.x;  // 819200
  if (idx < 163840) {  // result_new
    int bp = idx >> 10, k = idx & 1023;
    int sf = s_flat[bp];
    float v = b3[k];
#pragma unroll
    for (int z = 0; z < 12; ++z) v += resp[(size_t)z * 163840 + (size_t)sf * 1024 + k];
    out[idx] = v;
  } else if (idx < 327680) {  // hidden_new
    int rel = idx - 163840;
    int bp = rel >> 10, k = rel & 1023;
    out[idx] = h_new[(size_t)s_flat[bp] * 1024 + k];
  } else if (idx < 737280) {  // attn_scores_new (5,160,1,512)
    int rel = idx - 327680;
    int t = rel / 81920, r2 = rel % 81920;
    int bp = r2 >> 9, s = r2 & 511;
    int sf = s_flat[bp];
    float v = (t < 4) ? attn_sc_in[((size_t)t * 160 + sf) * 512 + s]
                      : attn[(size_t)sf * 512 + s];
    out[328480 + rel] = v;
  } else {  // mask_new
    int rel = idx - 737280;
    int bp = rel >> 9, s = rel & 511;
    int sf = s_flat[bp];
    float v = (s == new_sent[bp]) ? NEGC : mask_in[(size_t)sf * 512 + s];
    out[738080 + rel] = v;
  }
}

extern "C" void kernel_launch(void* const* d_in, const int* in_sizes, int n_in,
                              void* d_out, int out_size, void* d_ws, size_t ws_size,
                              hipStream_t stream) {
  const float* last_hidden = (const float*)d_in[0];
  const float* dec_in      = (const float*)d_in[1];
  const float* enc         = (const float*)d_in[2];
  const float* attn_sc_in  = (const float*)d_in[3];
  const float* mask_in     = (const float*)d_in[4];
  const float* ev          = (const float*)d_in[5];
  const int*   evidx       = (const int*)d_in[6];
  const float* W1  = (const float*)d_in[7];
  const float* b1  = (const float*)d_in[8];
  const float* W2  = (const float*)d_in[9];
  const float* b2  = (const float*)d_in[10];
  const float* W3  = (const float*)d_in[11];
  const float* b3  = (const float*)d_in[12];
  const float* Wih = (const float*)d_in[13];
  const float* Whh = (const float*)d_in[14];
  const float* bih = (const float*)d_in[15];
  const float* bhh = (const float*)d_in[16];
  float* out = (float*)d_out;
  float* ws = (float*)d_ws;

  float* resp    = ws;                    // 12*163840 (also GIp 4*160*3072 first)
  float* GIp     = ws;
  float* GHp     = ws + 1966080;          // also ctxp (8*163840)
  float* ctxp    = GHp;
  float* qp      = ws + 3932160;          // also ctxep (4*163840), then context
  float* ctxep   = qp;
  float* context = qp;
  float* h_new   = ws + 4587520;
  float* hb1     = ws + 4751360;
  float* attn    = ws + 4751520;
  float* align   = ws + 4833440;
  float* logsc   = ws + 4915360;
  int* sent      = (int*)(ws + 4916160);
  int* s_flat    = sent + 800;
  int* new_sent  = s_flat + 160;
  float* respB   = resp + 8 * 163840;     // W3b partial slices 8..11

  k_gemm_gru<<<dim3(48, 4, 2), dim3(256), 0, stream>>>(dec_in, last_hidden, Wih, Whh, GIp, GHp);
  gru_k<<<dim3(160), dim3(256), 0, stream>>>(GIp, GHp, bih, bhh, last_hidden, b1, h_new, hb1);
  k_gemm_qw3b<<<dim3(16, 4, 2), dim3(256), 0, stream>>>(h_new, W1, W3, qp, respB);
  scores_k<<<dim3(160, 4), dim3(256), 0, stream>>>(enc, qp, hb1, mask_in, attn);
  smtopk_k<<<dim3(160), dim3(256), 0, stream>>>(attn, ev, align, logsc, sent);
  beam_k<<<dim3(32), dim3(64), 0, stream>>>(logsc, sent, evidx, s_flat, new_sent, out);
  ctxe_k<<<dim3(160, 4), dim3(256), 0, stream>>>(enc, align, ctxep);
  k_gemm_w2<<<dim3(16, 8), dim3(256), 0, stream>>>(ctxep, W2, ctxp);
  sumctx_k<<<dim3(640), dim3(256), 0, stream>>>(ctxp, b2, context);
  k_gemm_w3a<<<dim3(16, 8), dim3(256), 0, stream>>>(context, W3, resp);
  pack_k<<<dim3(3200), dim3(256), 0, stream>>>(resp, b3, h_new, attn_sc_in, attn, mask_in,
                                               s_flat, new_sent, out);
}

// Round 3
// 322.948 us; speedup vs baseline: 1.3144x; 1.1424x over previous
//
#include <hip/hip_runtime.h>
#include <cstddef>

#define NEGC (-10000000000.0f)

// ---------------- workspace layout (float offsets) ----------------
// GIp  @ 0        : 8*160*3072 = 3,932,160   (later resp: 16*163840 = 2,621,440)
// GHp  @ 3932160  : 8*160*3072 = 3,932,160   (later ctxp: 8*163840 = 1,310,720)
// qp   @ 7864320  : 8*160*1024 = 1,310,720
// ctxep@ 9175040  : 4*160*1024 = 655,360
// h_new@ 9830400  : 163,840
// hb1  @ 9994240  : 160
// attn @ 9994400  : 81,920
// invZ @ 10076320 : 160
// logsc@ 10076480 : 800
// ints @ 10077280 : sent 800, s_flat 160, new_sent 160

// ---------------------------------------------------------------------------
// Skinny GEMM: C[z][160][64-strip] partial over a K-slice.
// AMODE 0: A plain [160][1024].  AMODE 1: A = bias[k] + sum of pcount partials
// (stride 163840).  AMODE 2: A = (sum of pcount partials) * scale[m].
// ---------------------------------------------------------------------------
template <bool NT, int AMODE>
__device__ __forceinline__ void gemm_body2(const float* __restrict__ A, int pcount,
                                           const float* __restrict__ bias,
                                           const float* __restrict__ scale,
                                           const float* __restrict__ W, int ldw, int woff,
                                           float* __restrict__ Co, int N, int Ktot,
                                           int n0, int z, int zcount) {
  __shared__ float As[160][36];
  __shared__ float Ws[64][36];
  const int KL = Ktot / zcount;
  const int kbase = z * KL;
  const int tid = threadIdx.x;
  const int tx = tid & 15, ty = tid >> 4;
  float acc[10][4];
#pragma unroll
  for (int i = 0; i < 10; ++i)
#pragma unroll
    for (int j = 0; j < 4; ++j) acc[i][j] = 0.f;

  for (int kt = 0; kt < KL; kt += 32) {
    const int kg = kbase + kt;
    for (int i = tid; i < 160 * 32; i += 256) {
      int m = i >> 5, kk = i & 31;
      float v;
      if (AMODE == 0) {
        v = A[(size_t)m * 1024 + kg + kk];
      } else if (AMODE == 1) {
        v = bias[kg + kk];
        for (int p = 0; p < pcount; ++p)
          v += A[(size_t)p * 163840 + (size_t)m * 1024 + kg + kk];
      } else {
        v = 0.f;
        for (int p = 0; p < pcount; ++p)
          v += A[(size_t)p * 163840 + (size_t)m * 1024 + kg + kk];
        v *= scale[m];
      }
      As[m][kk] = v;
    }
    if (NT) {
      for (int i = tid; i < 64 * 32; i += 256) {
        int n = i >> 5, kk = i & 31;
        Ws[n][kk] = W[(size_t)(n0 + n) * ldw + woff + kg + kk];
      }
    } else {
      for (int i = tid; i < 64 * 32; i += 256) {
        int kk = i >> 6, n = i & 63;
        Ws[n][kk] = W[(size_t)(kg + kk) * ldw + n0 + n];
      }
    }
    __syncthreads();
    for (int kk = 0; kk < 32; kk += 4) {
      float4 a[10], w[4];
#pragma unroll
      for (int i = 0; i < 10; ++i)
        a[i] = *reinterpret_cast<const float4*>(&As[ty + 16 * i][kk]);
#pragma unroll
      for (int j = 0; j < 4; ++j)
        w[j] = *reinterpret_cast<const float4*>(&Ws[tx + 16 * j][kk]);
#pragma unroll
      for (int i = 0; i < 10; ++i)
#pragma unroll
        for (int j = 0; j < 4; ++j) {
          acc[i][j] += a[i].x * w[j].x;
          acc[i][j] += a[i].y * w[j].y;
          acc[i][j] += a[i].z * w[j].z;
          acc[i][j] += a[i].w * w[j].w;
        }
    }
    __syncthreads();
  }
  float* Cb = Co + (size_t)z * 160 * N + n0;
#pragma unroll
  for (int i = 0; i < 10; ++i)
#pragma unroll
    for (int j = 0; j < 4; ++j)
      Cb[(size_t)(ty + 16 * i) * N + tx + 16 * j] = acc[i][j];
}

// GRU input/hidden GEMMs, one launch, N=3072, ksplit=gridDim.y
__global__ __launch_bounds__(256) void k_gemm_gru(const float* __restrict__ X,
                                                  const float* __restrict__ H0,
                                                  const float* __restrict__ Wih,
                                                  const float* __restrict__ Whh,
                                                  float* __restrict__ GIp,
                                                  float* __restrict__ GHp) {
  const float* A = blockIdx.z ? H0 : X;
  const float* W = blockIdx.z ? Whh : Wih;
  float* C = blockIdx.z ? GHp : GIp;
  gemm_body2<true, 0>(A, 0, nullptr, nullptr, W, 1024, 0, C, 3072, 1024,
                      blockIdx.x * 64, blockIdx.y, gridDim.y);
}

// q = h @ W1 (NN) and respB = h @ W3[:,1024:]^T (NT) in one launch
__global__ __launch_bounds__(256) void k_gemm_qw3b(const float* __restrict__ h,
                                                   const float* __restrict__ W1,
                                                   const float* __restrict__ W3,
                                                   float* __restrict__ qp,
                                                   float* __restrict__ respB) {
  if (blockIdx.z == 0)
    gemm_body2<false, 0>(h, 0, nullptr, nullptr, W1, 1024, 0, qp, 1024, 1024,
                         blockIdx.x * 64, blockIdx.y, gridDim.y);
  else
    gemm_body2<true, 0>(h, 0, nullptr, nullptr, W3, 2048, 1024, respB, 1024, 1024,
                        blockIdx.x * 64, blockIdx.y, gridDim.y);
}

// ctxp = ((sum of 4 ctxep partials) * invZ) @ W2^T
__global__ __launch_bounds__(256) void k_gemm_w2(const float* __restrict__ ctxep,
                                                 const float* __restrict__ invZ,
                                                 const float* __restrict__ W2,
                                                 float* __restrict__ ctxp) {
  gemm_body2<true, 2>(ctxep, 4, nullptr, invZ, W2, 1024, 0, ctxp, 1024, 1024,
                      blockIdx.x * 64, blockIdx.y, gridDim.y);
}

// resp[0..7] = (b2 + sum of 8 ctxp partials) @ W3[:, :1024]^T
__global__ __launch_bounds__(256) void k_gemm_w3a(const float* __restrict__ ctxp,
                                                  const float* __restrict__ b2,
                                                  const float* __restrict__ W3,
                                                  float* __restrict__ resp) {
  gemm_body2<true, 1>(ctxp, 8, b2, nullptr, W3, 2048, 0, resp, 1024, 1024,
                      blockIdx.x * 64, blockIdx.y, gridDim.y);
}

// ---------------------------------------------------------------------------
// GRU elementwise (8 partials) + fused hb1 = dot(h_new[b], b1)
// ---------------------------------------------------------------------------
__global__ __launch_bounds__(256) void gru_k(const float* __restrict__ GIp,
                                             const float* __restrict__ GHp,
                                             const float* __restrict__ bih,
                                             const float* __restrict__ bhh,
                                             const float* __restrict__ hprev,
                                             const float* __restrict__ b1,
                                             float* __restrict__ h_new,
                                             float* __restrict__ hb1) {
  int b = blockIdx.x, t = threadIdx.x;
  float dot = 0.f;
#pragma unroll
  for (int u = 0; u < 4; ++u) {
    int h = t + 256 * u;
    float gir = bih[h], giz = bih[1024 + h], gin = bih[2048 + h];
    float ghr = bhh[h], ghz = bhh[1024 + h], ghn = bhh[2048 + h];
#pragma unroll
    for (int z = 0; z < 8; ++z) {
      size_t base = ((size_t)z * 160 + b) * 3072 + h;
      gir += GIp[base]; giz += GIp[base + 1024]; gin += GIp[base + 2048];
      ghr += GHp[base]; ghz += GHp[base + 1024]; ghn += GHp[base + 2048];
    }
    float r = 1.0f / (1.0f + expf(-(gir + ghr)));
    float zg = 1.0f / (1.0f + expf(-(giz + ghz)));
    float n = tanhf(gin + r * ghn);
    float hp = hprev[(size_t)b * 1024 + h];
    float hn = (1.0f - zg) * n + zg * hp;
    h_new[(size_t)b * 1024 + h] = hn;
    dot += hn * b1[h];
  }
  __shared__ float red[256];
  red[t] = dot; __syncthreads();
  for (int o = 128; o > 0; o >>= 1) { if (t < o) red[t] += red[t + o]; __syncthreads(); }
  if (t == 0) hb1[b] = red[0];
}

// ---------------------------------------------------------------------------
// SINGLE pass over enc (LDS-staged): computes attn scores AND the
// unnormalized exp-weighted sum (ctxep partials). grid (160,4), 256 thr.
// ---------------------------------------------------------------------------
__global__ __launch_bounds__(256) void fused_enc_k(const float* __restrict__ enc,
                                                   const float* __restrict__ qp,
                                                   const float* __restrict__ hb1,
                                                   const float* __restrict__ maskin,
                                                   float* __restrict__ attn,
                                                   float* __restrict__ ctxep) {
  int b = blockIdx.x, c = blockIdx.y;
  int tid = threadIdx.x, wave = tid >> 6, lane = tid & 63;
  __shared__ float4 et[8 * 256];  // 8 rows x 1024 f = 32 KB
  __shared__ float4 qs[256];      // 4 KB
  float4 qa = {0.f, 0.f, 0.f, 0.f};
#pragma unroll
  for (int z = 0; z < 8; ++z) {
    const float4 tq = *reinterpret_cast<const float4*>(&qp[((size_t)z * 160 + b) * 1024 + 4 * tid]);
    qa.x += tq.x; qa.y += tq.y; qa.z += tq.z; qa.w += tq.w;
  }
  qs[tid] = qa;
  __syncthreads();
  float4 q[4];
#pragma unroll
  for (int j = 0; j < 4; ++j) q[j] = qs[lane + 64 * j];
  float hb = hb1[b] * 0.03125f;
  float4 acc[4];
#pragma unroll
  for (int j = 0; j < 4; ++j) acc[j] = make_float4(0.f, 0.f, 0.f, 0.f);

  const float4* encb = reinterpret_cast<const float4*>(enc) + ((size_t)b * 512 + c * 128) * 256;
  for (int it = 0; it < 16; ++it) {
    __syncthreads();
    const float4* src = encb + (size_t)it * 8 * 256;
#pragma unroll
    for (int u = 0; u < 8; ++u) et[u * 256 + tid] = src[u * 256 + tid];
    __syncthreads();
#pragma unroll
    for (int u = 0; u < 2; ++u) {
      int r = 2 * wave + u;
      float4 e[4];
#pragma unroll
      for (int j = 0; j < 4; ++j) e[j] = et[r * 256 + lane + 64 * j];
      float d = 0.f;
#pragma unroll
      for (int j = 0; j < 4; ++j)
        d += e[j].x * q[j].x + e[j].y * q[j].y + e[j].z * q[j].z + e[j].w * q[j].w;
#pragma unroll
      for (int off = 32; off > 0; off >>= 1) d += __shfl_xor(d, off);
      int s = c * 128 + it * 8 + r;
      float sc = d * 0.03125f + hb + maskin[(size_t)b * 512 + s];
      if (lane == 0) attn[(size_t)b * 512 + s] = sc;
      float w = expf(sc);
#pragma unroll
      for (int j = 0; j < 4; ++j) {
        acc[j].x += w * e[j].x; acc[j].y += w * e[j].y;
        acc[j].z += w * e[j].z; acc[j].w += w * e[j].w;
      }
    }
  }
  // cross-wave reduce (reuse et)
  __syncthreads();
  float4* red = et;
#pragma unroll
  for (int j = 0; j < 4; ++j) {
    red[wave * 64 + lane] = acc[j];
    __syncthreads();
    if (wave == 0) {
      float4 r0 = red[lane], r1 = red[64 + lane], r2 = red[128 + lane], r3 = red[192 + lane];
      float4 rr;
      rr.x = r0.x + r1.x + r2.x + r3.x;
      rr.y = r0.y + r1.y + r2.y + r3.y;
      rr.z = r0.z + r1.z + r2.z + r3.z;
      rr.w = r0.w + r1.w + r2.w + r3.w;
      reinterpret_cast<float4*>(ctxep)[((size_t)c * 160 + b) * 256 + lane + 64 * j] = rr;
    }
    __syncthreads();
  }
}

// ---------------------------------------------------------------------------
// softmax stats + top-5 on RAW scores (same order/ties as softmax top-k),
// writes invZ (no-max-sub normalizer, consistent with fused weights)
// ---------------------------------------------------------------------------
__global__ __launch_bounds__(256) void smtopk_k(const float* __restrict__ attn,
                                                const float* __restrict__ ev,
                                                float* __restrict__ invZ,
                                                float* __restrict__ logsc,
                                                int* __restrict__ sent) {
  int b = blockIdx.x, t = threadIdx.x;
  __shared__ float v[512];
  __shared__ float red[256];
  __shared__ int redi[256];
  float x0 = attn[(size_t)b * 512 + t], x1 = attn[(size_t)b * 512 + 256 + t];
  v[t] = x0; v[t + 256] = x1;
  red[t] = fmaxf(x0, x1); __syncthreads();
  for (int o = 128; o > 0; o >>= 1) { if (t < o) red[t] = fmaxf(red[t], red[t + o]); __syncthreads(); }
  float mx = red[0]; __syncthreads();
  red[t] = expf(x0 - mx) + expf(x1 - mx); __syncthreads();
  for (int o = 128; o > 0; o >>= 1) { if (t < o) red[t] += red[t + o]; __syncthreads(); }
  float Z = red[0]; __syncthreads();
  red[t] = expf(x0) + expf(x1); __syncthreads();
  for (int o = 128; o > 0; o >>= 1) { if (t < o) red[t] += red[t + o]; __syncthreads(); }
  if (t == 0) invZ[b] = 1.0f / red[0];
  __syncthreads();
  for (int r = 0; r < 5; ++r) {
    float bv; int bi;
    float v0 = v[t], v1 = v[t + 256];
    if (v1 > v0) { bv = v1; bi = t + 256; } else { bv = v0; bi = t; }
    red[t] = bv; redi[t] = bi; __syncthreads();
    for (int o = 128; o > 0; o >>= 1) {
      if (t < o) {
        if (red[t + o] > red[t] || (red[t + o] == red[t] && redi[t + o] < redi[t])) {
          red[t] = red[t + o]; redi[t] = redi[t + o];
        }
      }
      __syncthreads();
    }
    if (t == 0) {
      int id = redi[0];
      float a = expf(red[0] - mx) / Z;        // reference softmax value
      sent[b * 5 + r] = id;
      logsc[b * 5 + r] = -logf(a) + ev[b];
      v[id] = -3e38f;
    }
    __syncthreads();
  }
}

// ---------------------------------------------------------------------------
// beam re-ranking: per base group, 5 smallest of 25 (stable ascending)
// ---------------------------------------------------------------------------
__global__ void beam_k(const float* __restrict__ logsc, const int* __restrict__ sent,
                       const int* __restrict__ evidx_in, int* __restrict__ s_flat,
                       int* __restrict__ new_sent, float* __restrict__ out) {
  int g = blockIdx.x;
  int lane = threadIdx.x;  // 64
  float val = 1e30f;
  if (lane < 25) val = logsc[(g * 5 + lane / 5) * 5 + (lane % 5)];
  for (int j = 0; j < 5; ++j) {
    float bv = val; int bi = lane;
#pragma unroll
    for (int off = 1; off < 64; off <<= 1) {
      float ov = __shfl_xor(bv, off);
      int oi = __shfl_xor(bi, off);
      if (ov < bv || (ov == bv && oi < bi)) { bv = ov; bi = oi; }
    }
    if (lane == 0) {
      int ii = bi / 5, rr = bi % 5;
      int bp = g * 5 + j, sf = g * 5 + ii;
      s_flat[bp] = sf;
      int ns = sent[sf * 5 + rr];
      new_sent[bp] = ns;
      out[820000 + bp] = bv;
      for (int tt = 0; tt < 4; ++tt)
        out[327680 + bp * 5 + tt] = (float)evidx_in[sf * 4 + tt];
      out[327680 + bp * 5 + 4] = (float)ns;
    }
    if (lane == bi) val = 1e30f;
  }
}

// ---------------------------------------------------------------------------
// final gather/pack; resp has 16 partial slices (W3a 0..7, W3b 8..15)
// ---------------------------------------------------------------------------
__global__ void pack_k(const float* __restrict__ resp, const float* __restrict__ b3,
                       const float* __restrict__ h_new, const float* __restrict__ attn_sc_in,
                       const float* __restrict__ attn, const float* __restrict__ mask_in,
                       const int* __restrict__ s_flat, const int* __restrict__ new_sent,
                       float* __restrict__ out) {
  int idx = blockIdx.x * 256 + threadIdx.x;  // 819200
  if (idx < 163840) {  // result_new
    int bp = idx >> 10, k = idx & 1023;
    int sf = s_flat[bp];
    float v = b3[k];
#pragma unroll
    for (int z = 0; z < 16; ++z) v += resp[(size_t)z * 163840 + (size_t)sf * 1024 + k];
    out[idx] = v;
  } else if (idx < 327680) {  // hidden_new
    int rel = idx - 163840;
    int bp = rel >> 10, k = rel & 1023;
    out[idx] = h_new[(size_t)s_flat[bp] * 1024 + k];
  } else if (idx < 737280) {  // attn_scores_new (5,160,1,512)
    int rel = idx - 327680;
    int t = rel / 81920, r2 = rel % 81920;
    int bp = r2 >> 9, s = r2 & 511;
    int sf = s_flat[bp];
    float v = (t < 4) ? attn_sc_in[((size_t)t * 160 + sf) * 512 + s]
                      : attn[(size_t)sf * 512 + s];
    out[328480 + rel] = v;
  } else {  // mask_new
    int rel = idx - 737280;
    int bp = rel >> 9, s = rel & 511;
    int sf = s_flat[bp];
    float v = (s == new_sent[bp]) ? NEGC : mask_in[(size_t)sf * 512 + s];
    out[738080 + rel] = v;
  }
}

extern "C" void kernel_launch(void* const* d_in, const int* in_sizes, int n_in,
                              void* d_out, int out_size, void* d_ws, size_t ws_size,
                              hipStream_t stream) {
  const float* last_hidden = (const float*)d_in[0];
  const float* dec_in      = (const float*)d_in[1];
  const float* enc         = (const float*)d_in[2];
  const float* attn_sc_in  = (const float*)d_in[3];
  const float* mask_in     = (const float*)d_in[4];
  const float* ev          = (const float*)d_in[5];
  const int*   evidx       = (const int*)d_in[6];
  const float* W1  = (const float*)d_in[7];
  const float* b1  = (const float*)d_in[8];
  const float* W2  = (const float*)d_in[9];
  const float* b2  = (const float*)d_in[10];
  const float* W3  = (const float*)d_in[11];
  const float* b3  = (const float*)d_in[12];
  const float* Wih = (const float*)d_in[13];
  const float* Whh = (const float*)d_in[14];
  const float* bih = (const float*)d_in[15];
  const float* bhh = (const float*)d_in[16];
  float* out = (float*)d_out;
  float* ws = (float*)d_ws;

  float* GIp   = ws;                       // 8*160*3072
  float* GHp   = ws + 3932160;             // 8*160*3072
  float* resp  = ws;                       // 16*163840 (after GIp consumed)
  float* respB = resp + 8 * 163840;
  float* ctxp  = GHp;                      // 8*163840 (after GHp consumed)
  float* qp    = ws + 7864320;             // 8*160*1024
  float* ctxep = ws + 9175040;             // 4*160*1024
  float* h_new = ws + 9830400;
  float* hb1   = ws + 9994240;
  float* attn  = ws + 9994400;
  float* invZ  = ws + 10076320;
  float* logsc = ws + 10076480;
  int* sent     = (int*)(ws + 10077280);
  int* s_flat   = sent + 800;
  int* new_sent = s_flat + 160;

  k_gemm_gru<<<dim3(48, 8, 2), dim3(256), 0, stream>>>(dec_in, last_hidden, Wih, Whh, GIp, GHp);
  gru_k<<<dim3(160), dim3(256), 0, stream>>>(GIp, GHp, bih, bhh, last_hidden, b1, h_new, hb1);
  k_gemm_qw3b<<<dim3(16, 8, 2), dim3(256), 0, stream>>>(h_new, W1, W3, qp, respB);
  fused_enc_k<<<dim3(160, 4), dim3(256), 0, stream>>>(enc, qp, hb1, mask_in, attn, ctxep);
  smtopk_k<<<dim3(160), dim3(256), 0, stream>>>(attn, ev, invZ, logsc, sent);
  beam_k<<<dim3(32), dim3(64), 0, stream>>>(logsc, sent, evidx, s_flat, new_sent, out);
  k_gemm_w2<<<dim3(16, 8), dim3(256), 0, stream>>>(ctxep, invZ, W2, ctxp);
  k_gemm_w3a<<<dim3(16, 8), dim3(256), 0, stream>>>(ctxp, b2, W3, resp);
  pack_k<<<dim3(3200), dim3(256), 0, stream>>>(resp, b3, h_new, attn_sc_in, attn, mask_in,
                                               s_flat, new_sent, out);
}

// Round 4
// 279.044 us; speedup vs baseline: 1.5212x; 1.1573x over previous
//
#include <hip/hip_runtime.h>
#include <cstddef>

#define NEGC (-10000000000.0f)

// ---------------- workspace layout (float offsets) ----------------
// GIp  @ 0          : 8*160*3072 = 3,932,160  (later resp: 16*163840)
// GHp  @ 3,932,160  : 8*160*3072              (later ctxp: 8*163840)
// qp   @ 7,864,320  : 8*160*1024 = 1,310,720
// ctxep@ 9,175,040  : 8*163840   = 1,310,720
// h_new@ 10,485,760 : 163,840
// hb1  @ 10,649,600 : 160
// attn @ 10,649,760 : 81,920
// invZ @ 10,731,680 : 160
// ints @ 10,731,840 : s_flat 160, new_sent 160

// ---------------------------------------------------------------------------
// Skinny GEMM: C[z][160][64-strip] partial over a K-slice. LDS stride 44
// (16B-aligned rows, 2-way-max bank aliasing). float4 staging on NT path.
// AMODE 0: plain A[160][1024]. AMODE 1: A = bias[k] + sum of pcount partials
// (stride 163840). AMODE 2: A = (sum of pcount partials) * scale[m].
// ---------------------------------------------------------------------------
template <bool NT, int AMODE>
__device__ __forceinline__ void gemm_body3(const float* __restrict__ A, int pcount,
                                           const float* __restrict__ bias,
                                           const float* __restrict__ scale,
                                           const float* __restrict__ W, int ldw, int woff,
                                           float* __restrict__ Co, int N, int Ktot,
                                           int n0, int z, int zcount) {
  __shared__ float As[160][44];
  __shared__ float Ws[64][44];
  const int KL = Ktot / zcount;
  const int kbase = z * KL;
  const int tid = threadIdx.x;
  const int tx = tid & 15, ty = tid >> 4;
  float acc[10][4];
#pragma unroll
  for (int i = 0; i < 10; ++i)
#pragma unroll
    for (int j = 0; j < 4; ++j) acc[i][j] = 0.f;

  for (int kt = 0; kt < KL; kt += 32) {
    const int kg = kbase + kt;
    // stage As: 160 rows x 8 float4, 5 float4 per thread
#pragma unroll
    for (int k5 = 0; k5 < 5; ++k5) {
      int i = tid + 256 * k5;           // 0..1279
      int m = i >> 3, c4 = i & 7;
      float4 v;
      if (AMODE == 0) {
        v = *reinterpret_cast<const float4*>(&A[(size_t)m * 1024 + kg + 4 * c4]);
      } else {
        if (AMODE == 1) v = *reinterpret_cast<const float4*>(&bias[kg + 4 * c4]);
        else v = make_float4(0.f, 0.f, 0.f, 0.f);
        for (int p = 0; p < pcount; ++p) {
          float4 t = *reinterpret_cast<const float4*>(
              &A[(size_t)p * 163840 + (size_t)m * 1024 + kg + 4 * c4]);
          v.x += t.x; v.y += t.y; v.z += t.z; v.w += t.w;
        }
        if (AMODE == 2) { float s = scale[m]; v.x *= s; v.y *= s; v.z *= s; v.w *= s; }
      }
      *reinterpret_cast<float4*>(&As[m][4 * c4]) = v;
    }
    if (NT) {
#pragma unroll
      for (int k2 = 0; k2 < 2; ++k2) {
        int i = tid + 256 * k2;         // 0..511
        int n = i >> 3, c4 = i & 7;
        float4 v = *reinterpret_cast<const float4*>(
            &W[(size_t)(n0 + n) * ldw + woff + kg + 4 * c4]);
        *reinterpret_cast<float4*>(&Ws[n][4 * c4]) = v;
      }
    } else {
      for (int i = tid; i < 64 * 32; i += 256) {
        int kk = i >> 6, n = i & 63;
        Ws[n][kk] = W[(size_t)(kg + kk) * ldw + n0 + n];
      }
    }
    __syncthreads();
    for (int kk = 0; kk < 32; kk += 4) {
      float4 a[10], w[4];
#pragma unroll
      for (int i = 0; i < 10; ++i)
        a[i] = *reinterpret_cast<const float4*>(&As[ty + 16 * i][kk]);
#pragma unroll
      for (int j = 0; j < 4; ++j)
        w[j] = *reinterpret_cast<const float4*>(&Ws[tx + 16 * j][kk]);
#pragma unroll
      for (int i = 0; i < 10; ++i)
#pragma unroll
        for (int j = 0; j < 4; ++j) {
          acc[i][j] += a[i].x * w[j].x;
          acc[i][j] += a[i].y * w[j].y;
          acc[i][j] += a[i].z * w[j].z;
          acc[i][j] += a[i].w * w[j].w;
        }
    }
    __syncthreads();
  }
  float* Cb = Co + (size_t)z * 160 * N + n0;
#pragma unroll
  for (int i = 0; i < 10; ++i)
#pragma unroll
    for (int j = 0; j < 4; ++j)
      Cb[(size_t)(ty + 16 * i) * N + tx + 16 * j] = acc[i][j];
}

// GRU input/hidden GEMMs, one launch, N=3072, ksplit=gridDim.y
__global__ __launch_bounds__(256) void k_gemm_gru(const float* __restrict__ X,
                                                  const float* __restrict__ H0,
                                                  const float* __restrict__ Wih,
                                                  const float* __restrict__ Whh,
                                                  float* __restrict__ GIp,
                                                  float* __restrict__ GHp) {
  const float* A = blockIdx.z ? H0 : X;
  const float* W = blockIdx.z ? Whh : Wih;
  float* C = blockIdx.z ? GHp : GIp;
  gemm_body3<true, 0>(A, 0, nullptr, nullptr, W, 1024, 0, C, 3072, 1024,
                      blockIdx.x * 64, blockIdx.y, gridDim.y);
}

// q = h @ W1 (NN) and respB = h @ W3[:,1024:]^T (NT) in one launch
__global__ __launch_bounds__(256) void k_gemm_qw3b(const float* __restrict__ h,
                                                   const float* __restrict__ W1,
                                                   const float* __restrict__ W3,
                                                   float* __restrict__ qp,
                                                   float* __restrict__ respB) {
  if (blockIdx.z == 0)
    gemm_body3<false, 0>(h, 0, nullptr, nullptr, W1, 1024, 0, qp, 1024, 1024,
                         blockIdx.x * 64, blockIdx.y, gridDim.y);
  else
    gemm_body3<true, 0>(h, 0, nullptr, nullptr, W3, 2048, 1024, respB, 1024, 1024,
                        blockIdx.x * 64, blockIdx.y, gridDim.y);
}

// ctxp = ((sum of 8 ctxep partials) * invZ) @ W2^T
__global__ __launch_bounds__(256) void k_gemm_w2(const float* __restrict__ ctxep,
                                                 const float* __restrict__ invZ,
                                                 const float* __restrict__ W2,
                                                 float* __restrict__ ctxp) {
  gemm_body3<true, 2>(ctxep, 8, nullptr, invZ, W2, 1024, 0, ctxp, 1024, 1024,
                      blockIdx.x * 64, blockIdx.y, gridDim.y);
}

// resp[0..7] = (b2 + sum of 8 ctxp partials) @ W3[:, :1024]^T
__global__ __launch_bounds__(256) void k_gemm_w3a(const float* __restrict__ ctxp,
                                                  const float* __restrict__ b2,
                                                  const float* __restrict__ W3,
                                                  float* __restrict__ resp) {
  gemm_body3<true, 1>(ctxp, 8, b2, nullptr, W3, 2048, 0, resp, 1024, 1024,
                      blockIdx.x * 64, blockIdx.y, gridDim.y);
}

// ---------------------------------------------------------------------------
// GRU elementwise (8 partials) + fused hb1 = dot(h_new[b], b1)
// ---------------------------------------------------------------------------
__global__ __launch_bounds__(256) void gru_k(const float* __restrict__ GIp,
                                             const float* __restrict__ GHp,
                                             const float* __restrict__ bih,
                                             const float* __restrict__ bhh,
                                             const float* __restrict__ hprev,
                                             const float* __restrict__ b1,
                                             float* __restrict__ h_new,
                                             float* __restrict__ hb1) {
  int b = blockIdx.x, t = threadIdx.x;
  float dot = 0.f;
#pragma unroll
  for (int u = 0; u < 4; ++u) {
    int h = t + 256 * u;
    float gir = bih[h], giz = bih[1024 + h], gin = bih[2048 + h];
    float ghr = bhh[h], ghz = bhh[1024 + h], ghn = bhh[2048 + h];
#pragma unroll
    for (int z = 0; z < 8; ++z) {
      size_t base = ((size_t)z * 160 + b) * 3072 + h;
      gir += GIp[base]; giz += GIp[base + 1024]; gin += GIp[base + 2048];
      ghr += GHp[base]; ghz += GHp[base + 1024]; ghn += GHp[base + 2048];
    }
    float r = 1.0f / (1.0f + expf(-(gir + ghr)));
    float zg = 1.0f / (1.0f + expf(-(giz + ghz)));
    float n = tanhf(gin + r * ghn);
    float hp = hprev[(size_t)b * 1024 + h];
    float hn = (1.0f - zg) * n + zg * hp;
    h_new[(size_t)b * 1024 + h] = hn;
    dot += hn * b1[h];
  }
  __shared__ float red[256];
  red[t] = dot; __syncthreads();
  for (int o = 128; o > 0; o >>= 1) { if (t < o) red[t] += red[t + o]; __syncthreads(); }
  if (t == 0) hb1[b] = red[0];
}

// ---------------------------------------------------------------------------
// SINGLE pass over enc, register-direct (no LDS staging, no barriers in the
// hot loop): each wave owns 16 rows, 4 rows unrolled -> 16 dwordx4 loads in
// flight. Computes attn scores AND unnormalized exp-weighted enc sum.
// grid (160, 8) x 256 threads; ctxep gets 8 partial chunks.
// ---------------------------------------------------------------------------
__global__ __launch_bounds__(256) void enc_k(const float* __restrict__ enc,
                                             const float* __restrict__ qp,
                                             const float* __restrict__ hb1,
                                             const float* __restrict__ maskin,
                                             float* __restrict__ attn,
                                             float* __restrict__ ctxep) {
  int b = blockIdx.x, c = blockIdx.y;
  int tid = threadIdx.x, wave = tid >> 6, lane = tid & 63;
  __shared__ float4 qs[256];
  float4 qa = {0.f, 0.f, 0.f, 0.f};
#pragma unroll
  for (int z = 0; z < 8; ++z) {
    float4 t = *reinterpret_cast<const float4*>(&qp[((size_t)z * 160 + b) * 1024 + 4 * tid]);
    qa.x += t.x; qa.y += t.y; qa.z += t.z; qa.w += t.w;
  }
  qs[tid] = qa;
  __syncthreads();
  float4 q[4];
#pragma unroll
  for (int j = 0; j < 4; ++j) q[j] = qs[lane + 64 * j];
  float hb = hb1[b] * 0.03125f;
  float4 acc[4];
#pragma unroll
  for (int j = 0; j < 4; ++j) acc[j] = make_float4(0.f, 0.f, 0.f, 0.f);

  int row0 = c * 64 + wave * 16;
  const float4* encb = reinterpret_cast<const float4*>(enc) + ((size_t)b * 512 + row0) * 256;
  const float* mrow = &maskin[(size_t)b * 512 + row0];
  float* arow = &attn[(size_t)b * 512 + row0];

  for (int it = 0; it < 4; ++it) {
    float4 e[4][4];
#pragma unroll
    for (int r = 0; r < 4; ++r)
#pragma unroll
      for (int j = 0; j < 4; ++j)
        e[r][j] = encb[(size_t)(it * 4 + r) * 256 + lane + 64 * j];
#pragma unroll
    for (int r = 0; r < 4; ++r) {
      float d = 0.f;
#pragma unroll
      for (int j = 0; j < 4; ++j)
        d += e[r][j].x * q[j].x + e[r][j].y * q[j].y + e[r][j].z * q[j].z + e[r][j].w * q[j].w;
#pragma unroll
      for (int off = 32; off > 0; off >>= 1) d += __shfl_xor(d, off);
      int s = it * 4 + r;
      float sc = d * 0.03125f + hb + mrow[s];
      if (lane == 0) arow[s] = sc;
      float w = expf(sc);
#pragma unroll
      for (int j = 0; j < 4; ++j) {
        acc[j].x += w * e[r][j].x; acc[j].y += w * e[r][j].y;
        acc[j].z += w * e[r][j].z; acc[j].w += w * e[r][j].w;
      }
    }
  }
  // cross-wave reduce (reuse qs as scratch)
  __syncthreads();
  float4* red = qs;
#pragma unroll
  for (int j = 0; j < 4; ++j) {
    red[wave * 64 + lane] = acc[j];
    __syncthreads();
    if (wave == 0) {
      float4 r0 = red[lane], r1 = red[64 + lane], r2 = red[128 + lane], r3 = red[192 + lane];
      float4 rr;
      rr.x = r0.x + r1.x + r2.x + r3.x;
      rr.y = r0.y + r1.y + r2.y + r3.y;
      rr.z = r0.z + r1.z + r2.z + r3.z;
      rr.w = r0.w + r1.w + r2.w + r3.w;
      reinterpret_cast<float4*>(ctxep)[((size_t)c * 160 + b) * 256 + lane + 64 * j] = rr;
    }
    __syncthreads();
  }
}

// ---------------------------------------------------------------------------
// merged softmax-stats + top-5 + beam re-rank: 32 blocks x 256 threads,
// each block owns one base group (5 batch rows). logsc/sent stay in LDS.
// ---------------------------------------------------------------------------
__global__ __launch_bounds__(256) void smtopk_beam_k(const float* __restrict__ attn,
                                                     const float* __restrict__ ev,
                                                     const int* __restrict__ evidx_in,
                                                     float* __restrict__ invZ,
                                                     int* __restrict__ s_flat,
                                                     int* __restrict__ new_sent,
                                                     float* __restrict__ out) {
  int g = blockIdx.x, t = threadIdx.x;
  __shared__ float v[512];
  __shared__ float red[256];
  __shared__ int redi[256];
  __shared__ float lsc[25];
  __shared__ int snt[25];

  for (int i = 0; i < 5; ++i) {
    int b = g * 5 + i;
    float x0 = attn[(size_t)b * 512 + t], x1 = attn[(size_t)b * 512 + 256 + t];
    v[t] = x0; v[t + 256] = x1;
    red[t] = fmaxf(x0, x1); __syncthreads();
    for (int o = 128; o > 0; o >>= 1) { if (t < o) red[t] = fmaxf(red[t], red[t + o]); __syncthreads(); }
    float mx = red[0]; __syncthreads();
    red[t] = expf(x0 - mx) + expf(x1 - mx); __syncthreads();
    for (int o = 128; o > 0; o >>= 1) { if (t < o) red[t] += red[t + o]; __syncthreads(); }
    float Z = red[0]; __syncthreads();
    red[t] = expf(x0) + expf(x1); __syncthreads();
    for (int o = 128; o > 0; o >>= 1) { if (t < o) red[t] += red[t + o]; __syncthreads(); }
    if (t == 0) invZ[b] = 1.0f / red[0];
    __syncthreads();
    float evb = ev[b];
    for (int r = 0; r < 5; ++r) {
      float bv; int bi;
      float v0 = v[t], v1 = v[t + 256];
      if (v1 > v0) { bv = v1; bi = t + 256; } else { bv = v0; bi = t; }
      red[t] = bv; redi[t] = bi; __syncthreads();
      for (int o = 128; o > 0; o >>= 1) {
        if (t < o) {
          if (red[t + o] > red[t] || (red[t + o] == red[t] && redi[t + o] < redi[t])) {
            red[t] = red[t + o]; redi[t] = redi[t + o];
          }
        }
        __syncthreads();
      }
      if (t == 0) {
        int id = redi[0];
        float a = expf(red[0] - mx) / Z;   // reference softmax value
        snt[i * 5 + r] = id;
        lsc[i * 5 + r] = -logf(a) + evb;
        v[id] = -3e38f;
      }
      __syncthreads();
    }
  }
  __syncthreads();
  if (t < 64) {
    float val = (t < 25) ? lsc[(t / 5) * 5 + (t % 5)] : 1e30f;
    for (int j = 0; j < 5; ++j) {
      float bv = val; int bi = t;
#pragma unroll
      for (int off = 1; off < 64; off <<= 1) {
        float ov = __shfl_xor(bv, off);
        int oi = __shfl_xor(bi, off);
        if (ov < bv || (ov == bv && oi < bi)) { bv = ov; bi = oi; }
      }
      if (t == 0) {
        int ii = bi / 5, rr = bi % 5;
        int bp = g * 5 + j, sf = g * 5 + ii;
        s_flat[bp] = sf;
        int ns = snt[ii * 5 + rr];
        new_sent[bp] = ns;
        out[820000 + bp] = bv;
        for (int tt = 0; tt < 4; ++tt)
          out[327680 + bp * 5 + tt] = (float)evidx_in[sf * 4 + tt];
        out[327680 + bp * 5 + 4] = (float)ns;
      }
      if (t == bi) val = 1e30f;
    }
  }
}

// ---------------------------------------------------------------------------
// final gather/pack; resp has 16 partial slices (W3a 0..7, W3b 8..15)
// ---------------------------------------------------------------------------
__global__ void pack_k(const float* __restrict__ resp, const float* __restrict__ b3,
                       const float* __restrict__ h_new, const float* __restrict__ attn_sc_in,
                       const float* __restrict__ attn, const float* __restrict__ mask_in,
                       const int* __restrict__ s_flat, const int* __restrict__ new_sent,
                       float* __restrict__ out) {
  int idx = blockIdx.x * 256 + threadIdx.x;  // 819200
  if (idx < 163840) {  // result_new
    int bp = idx >> 10, k = idx & 1023;
    int sf = s_flat[bp];
    float v = b3[k];
#pragma unroll
    for (int z = 0; z < 16; ++z) v += resp[(size_t)z * 163840 + (size_t)sf * 1024 + k];
    out[idx] = v;
  } else if (idx < 327680) {  // hidden_new
    int rel = idx - 163840;
    int bp = rel >> 10, k = rel & 1023;
    out[idx] = h_new[(size_t)s_flat[bp] * 1024 + k];
  } else if (idx < 737280) {  // attn_scores_new (5,160,1,512)
    int rel = idx - 327680;
    int t = rel / 81920, r2 = rel % 81920;
    int bp = r2 >> 9, s = r2 & 511;
    int sf = s_flat[bp];
    float v = (t < 4) ? attn_sc_in[((size_t)t * 160 + sf) * 512 + s]
                      : attn[(size_t)sf * 512 + s];
    out[328480 + rel] = v;
  } else {  // mask_new
    int rel = idx - 737280;
    int bp = rel >> 9, s = rel & 511;
    int sf = s_flat[bp];
    float v = (s == new_sent[bp]) ? NEGC : mask_in[(size_t)sf * 512 + s];
    out[738080 + rel] = v;
  }
}

extern "C" void kernel_launch(void* const* d_in, const int* in_sizes, int n_in,
                              void* d_out, int out_size, void* d_ws, size_t ws_size,
                              hipStream_t stream) {
  const float* last_hidden = (const float*)d_in[0];
  const float* dec_in      = (const float*)d_in[1];
  const float* enc         = (const float*)d_in[2];
  const float* attn_sc_in  = (const float*)d_in[3];
  const float* mask_in     = (const float*)d_in[4];
  const float* ev          = (const float*)d_in[5];
  const int*   evidx       = (const int*)d_in[6];
  const float* W1  = (const float*)d_in[7];
  const float* b1  = (const float*)d_in[8];
  const float* W2  = (const float*)d_in[9];
  const float* b2  = (const float*)d_in[10];
  const float* W3  = (const float*)d_in[11];
  const float* b3  = (const float*)d_in[12];
  const float* Wih = (const float*)d_in[13];
  const float* Whh = (const float*)d_in[14];
  const float* bih = (const float*)d_in[15];
  const float* bhh = (const float*)d_in[16];
  float* out = (float*)d_out;
  float* ws = (float*)d_ws;

  float* GIp   = ws;                        // 8*160*3072
  float* GHp   = ws + 3932160;              // 8*160*3072
  float* resp  = ws;                        // 16*163840 (after GIp consumed)
  float* respB = resp + 8 * 163840;
  float* ctxp  = GHp;                       // 8*163840 (after GHp consumed)
  float* qp    = ws + 7864320;              // 8*160*1024
  float* ctxep = ws + 9175040;              // 8*163840
  float* h_new = ws + 10485760;
  float* hb1   = ws + 10649600;
  float* attn  = ws + 10649760;
  float* invZ  = ws + 10731680;
  int* s_flat   = (int*)(ws + 10731840);
  int* new_sent = s_flat + 160;

  k_gemm_gru<<<dim3(48, 8, 2), dim3(256), 0, stream>>>(dec_in, last_hidden, Wih, Whh, GIp, GHp);
  gru_k<<<dim3(160), dim3(256), 0, stream>>>(GIp, GHp, bih, bhh, last_hidden, b1, h_new, hb1);
  k_gemm_qw3b<<<dim3(16, 8, 2), dim3(256), 0, stream>>>(h_new, W1, W3, qp, respB);
  enc_k<<<dim3(160, 8), dim3(256), 0, stream>>>(enc, qp, hb1, mask_in, attn, ctxep);
  smtopk_beam_k<<<dim3(32), dim3(256), 0, stream>>>(attn, ev, evidx, invZ, s_flat, new_sent, out);
  k_gemm_w2<<<dim3(16, 8), dim3(256), 0, stream>>>(ctxep, invZ, W2, ctxp);
  k_gemm_w3a<<<dim3(16, 8), dim3(256), 0, stream>>>(ctxp, b2, W3, resp);
  pack_k<<<dim3(3200), dim3(256), 0, stream>>>(resp, b3, h_new, attn_sc_in, attn, mask_in,
                                               s_flat, new_sent, out);
}